// Round 1
// baseline (491.738 us; speedup 1.0000x reference)
//
#include <hip/hip_runtime.h>
#include <math.h>

#define NPB 128            // nodes per block in deconv
#define EPS 1e-5f

// ---------------------------------------------------------------------------
// Kernel 1: octree deconv (27-tap gather-GEMM) + fused GN statistics
//   block = 256 threads, tile = 128 nodes x 32 cout
//   thread (ns, cs): ns = t>>3 in [0,32) -> nodes ns*4..ns*4+3
//                    cs = t&7  in [0,8)  -> couts cs*4..cs*4+3
//   staging: nn = t>>1 in [0,128) node, ci0 = (t&1)*16 channel half
// ---------------------------------------------------------------------------
__device__ __forceinline__ void load_x_frag(const float* __restrict__ data,
                                            const int* __restrict__ neigh,
                                            int nstage, int N, int k, int ci0,
                                            float xr[16]) {
    if (nstage < N) {
        const int ng = neigh[nstage * 27 + k];
        const float4* src = (const float4*)(data + (size_t)ng * 32 + ci0);
        float4 a = src[0], b = src[1], c = src[2], d = src[3];
        xr[0]  = a.x; xr[1]  = a.y; xr[2]  = a.z; xr[3]  = a.w;
        xr[4]  = b.x; xr[5]  = b.y; xr[6]  = b.z; xr[7]  = b.w;
        xr[8]  = c.x; xr[9]  = c.y; xr[10] = c.z; xr[11] = c.w;
        xr[12] = d.x; xr[13] = d.y; xr[14] = d.z; xr[15] = d.w;
    } else {
#pragma unroll
        for (int i = 0; i < 16; ++i) xr[i] = 0.f;
    }
}

__global__ __launch_bounds__(256) void deconv_stats_kernel(
    const float* __restrict__ data, const float* __restrict__ W,
    const int* __restrict__ neigh, const int* __restrict__ batch_id,
    float* __restrict__ out, float* __restrict__ gs1, float* __restrict__ gs2,
    float* __restrict__ gcnt, int N) {
    __shared__ float XT[32 * NPB];   // XT[ci][node] transposed tile, 16 KB
    __shared__ float WS[32 * 32];    // W[k][ci][co], 4 KB
    __shared__ float ls1[8 * 32];    // per-(batch,ch) sum h
    __shared__ float ls2[8 * 32];    // per-(batch,ch) sum h^2
    __shared__ float lcnt[8];        // per-batch node count

    const int t = threadIdx.x;
    const int base = blockIdx.x * NPB;

    ls1[t] = 0.f;
    ls2[t] = 0.f;
    if (t < 8) lcnt[t] = 0.f;

    const int ns = t >> 3;           // node slot
    const int cs = t & 7;            // cout slot
    const int nn = t >> 1;           // staging node
    const int ci0 = (t & 1) * 16;    // staging channel half
    const int nstage = base + nn;

    float acc[4][4];
#pragma unroll
    for (int j = 0; j < 4; ++j)
#pragma unroll
        for (int c = 0; c < 4; ++c) acc[j][c] = 0.f;

    // prefetch tap 0 into registers
    float xr[16];
    float4 wr = ((const float4*)W)[t];
    load_x_frag(data, neigh, nstage, N, 0, ci0, xr);

    for (int k = 0; k < 27; ++k) {
        __syncthreads();             // previous tile consumed
        ((float4*)WS)[t] = wr;
#pragma unroll
        for (int i = 0; i < 16; ++i) XT[(ci0 + i) * NPB + nn] = xr[i];
        __syncthreads();             // tile visible

        // prefetch tap k+1 (overlaps with compute below)
        if (k + 1 < 27) {
            wr = ((const float4*)(W + (k + 1) * 1024))[t];
            load_x_frag(data, neigh, nstage, N, k + 1, ci0, xr);
        }

        const float* xrow = XT + ns * 4;
        const float* wrow = WS + cs * 4;
#pragma unroll
        for (int ci = 0; ci < 32; ++ci) {
            float4 xv = *(const float4*)(xrow + ci * NPB);  // 4 nodes
            float4 wv = *(const float4*)(wrow + ci * 32);   // 4 couts
            acc[0][0] = fmaf(xv.x, wv.x, acc[0][0]);
            acc[0][1] = fmaf(xv.x, wv.y, acc[0][1]);
            acc[0][2] = fmaf(xv.x, wv.z, acc[0][2]);
            acc[0][3] = fmaf(xv.x, wv.w, acc[0][3]);
            acc[1][0] = fmaf(xv.y, wv.x, acc[1][0]);
            acc[1][1] = fmaf(xv.y, wv.y, acc[1][1]);
            acc[1][2] = fmaf(xv.y, wv.z, acc[1][2]);
            acc[1][3] = fmaf(xv.y, wv.w, acc[1][3]);
            acc[2][0] = fmaf(xv.z, wv.x, acc[2][0]);
            acc[2][1] = fmaf(xv.z, wv.y, acc[2][1]);
            acc[2][2] = fmaf(xv.z, wv.z, acc[2][2]);
            acc[2][3] = fmaf(xv.z, wv.w, acc[2][3]);
            acc[3][0] = fmaf(xv.w, wv.x, acc[3][0]);
            acc[3][1] = fmaf(xv.w, wv.y, acc[3][1]);
            acc[3][2] = fmaf(xv.w, wv.z, acc[3][2]);
            acc[3][3] = fmaf(xv.w, wv.w, acc[3][3]);
        }
    }

    // epilogue: write pre-norm h, accumulate GN stats into LDS
#pragma unroll
    for (int j = 0; j < 4; ++j) {
        const int n = base + ns * 4 + j;
        if (n < N) {
            float4 v = make_float4(acc[j][0], acc[j][1], acc[j][2], acc[j][3]);
            *(float4*)(out + (size_t)n * 32 + cs * 4) = v;
            const int b = batch_id[n];
            float* p1 = ls1 + b * 32 + cs * 4;
            float* p2 = ls2 + b * 32 + cs * 4;
            atomicAdd(p1 + 0, v.x);
            atomicAdd(p1 + 1, v.y);
            atomicAdd(p1 + 2, v.z);
            atomicAdd(p1 + 3, v.w);
            atomicAdd(p2 + 0, v.x * v.x);
            atomicAdd(p2 + 1, v.y * v.y);
            atomicAdd(p2 + 2, v.z * v.z);
            atomicAdd(p2 + 3, v.w * v.w);
            if (cs == 0) atomicAdd(&lcnt[b], 1.0f);
        }
    }
    __syncthreads();

    // flush block-level stats to global (skip zeros: adding 0 is a no-op)
    {
        float v1 = ls1[t];
        if (v1 != 0.f) atomicAdd(&gs1[t], v1);
        float v2 = ls2[t];
        if (v2 != 0.f) atomicAdd(&gs2[t], v2);
        if (t < 8) {
            float c = lcnt[t];
            if (c != 0.f) atomicAdd(&gcnt[t], c);
        }
    }
}

// ---------------------------------------------------------------------------
// Kernel 2: fold stats -> per-(batch,channel) affine (scale, shift)
//   1 block x 256 threads; t -> (b = t>>5, c = t&31); group = c>>2 (Cg = 4)
// ---------------------------------------------------------------------------
__global__ void gn_finalize_kernel(const float* __restrict__ gs1,
                                   const float* __restrict__ gs2,
                                   const float* __restrict__ gcnt,
                                   const float* __restrict__ gamma,
                                   const float* __restrict__ beta,
                                   float* __restrict__ scale,
                                   float* __restrict__ shift) {
    const int t = threadIdx.x;
    const int b = t >> 5;
    const int c = t & 31;
    const int g = c >> 2;

    const float cnt = gcnt[b] * 4.0f;           // n_b * C/G
    const float inv_cnt = 1.0f / (cnt + EPS);
    const float* p1 = gs1 + b * 32 + g * 4;
    const float* p2 = gs2 + b * 32 + g * 4;
    const float s1 = p1[0] + p1[1] + p1[2] + p1[3];
    const float s2 = p2[0] + p2[1] + p2[2] + p2[3];
    const float mean = s1 * inv_cnt;
    const float var = s2 * inv_cnt - mean * mean;
    const float inv_std = rsqrtf(var + EPS);
    const float sc = inv_std * gamma[c];
    scale[t] = sc;
    shift[t] = beta[c] - mean * sc;
}

// ---------------------------------------------------------------------------
// Kernel 3: apply GN affine + ReLU in-place on d_out (float4, streaming)
// ---------------------------------------------------------------------------
__global__ __launch_bounds__(256) void gn_relu_kernel(
    float* __restrict__ out, const int* __restrict__ batch_id,
    const float* __restrict__ scale, const float* __restrict__ shift, int N) {
    const int idx = blockIdx.x * 256 + threadIdx.x;
    if (idx >= N * 8) return;                   // N*32 elems / 4 per thread
    const int e0 = idx * 4;
    const int n = e0 >> 5;
    const int c = e0 & 31;
    const int b = batch_id[n];
    float4 h = *(float4*)(out + (size_t)e0);
    const float4 sc = *(const float4*)(scale + b * 32 + c);
    const float4 sh = *(const float4*)(shift + b * 32 + c);
    float4 y;
    y.x = fmaxf(fmaf(h.x, sc.x, sh.x), 0.f);
    y.y = fmaxf(fmaf(h.y, sc.y, sh.y), 0.f);
    y.z = fmaxf(fmaf(h.z, sc.z, sh.z), 0.f);
    y.w = fmaxf(fmaf(h.w, sc.w, sh.w), 0.f);
    *(float4*)(out + (size_t)e0) = y;
}

// ---------------------------------------------------------------------------
extern "C" void kernel_launch(void* const* d_in, const int* in_sizes, int n_in,
                              void* d_out, int out_size, void* d_ws, size_t ws_size,
                              hipStream_t stream) {
    const float* data     = (const float*)d_in[0];   // [N,32]
    const float* weights  = (const float*)d_in[1];   // [27,32,32]
    const float* gamma    = (const float*)d_in[2];   // [32]
    const float* beta     = (const float*)d_in[3];   // [32]
    const int*   neigh    = (const int*)d_in[4];     // [N,27]
    const int*   batch_id = (const int*)d_in[5];     // [N]
    const int N = in_sizes[0] / 32;
    float* out = (float*)d_out;

    // workspace layout (floats): gs1[256] gs2[256] gcnt[8] scale[256] shift[256]
    float* ws = (float*)d_ws;
    float* gs1   = ws;
    float* gs2   = ws + 256;
    float* gcnt  = ws + 512;
    float* scale = ws + 520;
    float* shift = ws + 776;

    hipMemsetAsync(ws, 0, 520 * sizeof(float), stream);

    const int nblocks = (N + NPB - 1) / NPB;
    hipLaunchKernelGGL(deconv_stats_kernel, dim3(nblocks), dim3(256), 0, stream,
                       data, weights, neigh, batch_id, out, gs1, gs2, gcnt, N);

    hipLaunchKernelGGL(gn_finalize_kernel, dim3(1), dim3(256), 0, stream,
                       gs1, gs2, gcnt, gamma, beta, scale, shift);

    const int n4 = N * 8;
    hipLaunchKernelGGL(gn_relu_kernel, dim3((n4 + 255) / 256), dim3(256), 0,
                       stream, out, batch_id, scale, shift, N);
}